// Round 3
// baseline (1350.443 us; speedup 1.0000x reference)
//
#include <hip/hip_runtime.h>
#include <hip/hip_bf16.h>

#define NB 16
#define NP 4096
#define MS 1024
#define NN 65536
#define FIN 64
#define FOUT 128

// DPP cumulative-max step: combine with row-shifted/broadcast neighbor (VALU pipe, no LDS)
template <int CTRL>
__device__ __forceinline__ unsigned long long dpp_max_step(unsigned long long k) {
    unsigned lo = (unsigned)k, hi = (unsigned)(k >> 32);
    unsigned plo = (unsigned)__builtin_amdgcn_update_dpp(0, (int)lo, CTRL, 0xf, 0xf, true);
    unsigned phi = (unsigned)__builtin_amdgcn_update_dpp(0, (int)hi, CTRL, 0xf, 0xf, true);
    unsigned long long pk = ((unsigned long long)phi << 32) | plo;   // invalid lanes -> 0 (identity)
    return pk > k ? pk : k;
}

// merge two sorted (d asc, idx asc) 16-lists -> top-16, lex order matches top_k ties
__device__ __forceinline__ void merge16(const float* __restrict__ dA, const int* __restrict__ iA,
                                        const float* __restrict__ dB, const int* __restrict__ iB,
                                        float* __restrict__ oD, int* __restrict__ oI) {
    int x = 0, y = 0;
#pragma unroll
    for (int r = 0; r < 16; r++) {
        int xc = x < 16 ? x : 15, yc = y < 16 ? y : 15;
        float va = dA[xc]; int ja = iA[xc];
        float vb = dB[yc]; int jb = iB[yc];
        bool ta = (y >= 16) || ((x < 16) && (va < vb || (va == vb && ja < jb)));
        oD[r] = ta ? va : vb;
        oI[r] = ta ? ja : jb;
        if (ta) x++; else y++;
    }
}

// ---------------------------------------------------------------- front: FPS + GEMM + xnorm fused
__global__ __launch_bounds__(256) void front_kernel(
        const float* __restrict__ pos, const float* __restrict__ feat,
        const float* __restrict__ W, const float* __restrict__ bias,
        int* __restrict__ fps_idx, float* __restrict__ out_pos, float* __restrict__ out_batch,
        float* __restrict__ xnorm, __hip_bfloat16* __restrict__ hout,
        float* __restrict__ gsum, float* __restrict__ gsq) {
    __shared__ float smem[13328];
    const int t = threadIdx.x;
    const int b = blockIdx.x;
    if (b < 16) {
        // ---------------- FPS: 256 threads, 16 pts/thread in registers
        float* plds = smem;                                   // 12288 floats
        int* idxL = (int*)(smem + 12288);                     // 1024 ints
        unsigned long long* rk = (unsigned long long*)(smem + 13312);  // 8 u64
        const float* pb = pos + (size_t)b * NP * 3;
#pragma unroll
        for (int i = 0; i < 48; i++) { int id = t + 256 * i; plds[id] = pb[id]; }
        __syncthreads();
        float px[16], py[16], pz[16], dist[16];
#pragma unroll
        for (int i = 0; i < 16; i++) {
            int p = t + 256 * i;
            px[i] = plds[p * 3 + 0]; py[i] = plds[p * 3 + 1]; pz[i] = plds[p * 3 + 2];
            dist[i] = INFINITY;
        }
        float lx = plds[0], ly = plds[1], lz = plds[2];
        if (t == 0) idxL[0] = 0;
        const int ln = t & 63, wv = t >> 6;
        for (int m = 1; m < MS; m++) {
            // phase A: independent distance updates (pipelined, no serial chain)
#pragma unroll
            for (int i = 0; i < 16; i++) {
                float dx = px[i] - lx, dy = py[i] - ly, dz = pz[i] - lz;
                float d = dx * dx + dy * dy + dz * dz;
                dist[i] = fminf(dist[i], d);
            }
            // in-thread argmax: 4-level tree; pairing (i, i+8) keeps p ascending so
            // strict > selects the right only when strictly bigger -> ties keep lowest idx
            float d1[8]; int i1[8];
#pragma unroll
            for (int i = 0; i < 8; i++) {
                bool g = dist[i + 8] > dist[i];
                d1[i] = g ? dist[i + 8] : dist[i]; i1[i] = g ? (i + 8) : i;
            }
            float d2[4]; int i2[4];
#pragma unroll
            for (int i = 0; i < 4; i++) {
                bool g = d2[i] = 0, gg = d1[i + 4] > d1[i];
                (void)g;
                d2[i] = gg ? d1[i + 4] : d1[i]; i2[i] = gg ? i1[i + 4] : i1[i];
            }
            float d3[2]; int i3[2];
#pragma unroll
            for (int i = 0; i < 2; i++) {
                bool g = d2[i + 2] > d2[i];
                d3[i] = g ? d2[i + 2] : d2[i]; i3[i] = g ? i2[i + 2] : i2[i];
            }
            bool g3 = d3[1] > d3[0];
            float bd = g3 ? d3[1] : d3[0];
            int bi = g3 ? i3[1] : i3[0];
            int bp = t + (bi << 8);
            // pack: d>=0 so float bits are order-preserving; ~bp makes smaller idx win ties
            unsigned long long key =
                ((unsigned long long)__float_as_uint(bd) << 32) | (unsigned)(~bp);
            // wave cumulative-max via DPP (VALU pipe): lane 63 ends with wave max
            key = dpp_max_step<0x111>(key);   // row_shr:1
            key = dpp_max_step<0x112>(key);   // row_shr:2
            key = dpp_max_step<0x114>(key);   // row_shr:4
            key = dpp_max_step<0x118>(key);   // row_shr:8
            key = dpp_max_step<0x142>(key);   // row_bcast15
            key = dpp_max_step<0x143>(key);   // row_bcast31
            const int par = (m & 1) * 4;
            if (ln == 63) rk[par + wv] = key;
            __syncthreads();
            unsigned long long k0 = rk[par + 0], k1 = rk[par + 1];
            unsigned long long k2 = rk[par + 2], k3 = rk[par + 3];
            unsigned long long ka = k0 > k1 ? k0 : k1;
            unsigned long long kb = k2 > k3 ? k2 : k3;
            unsigned long long kw = ka > kb ? ka : kb;
            bp = (int)(~(unsigned)kw) & 0xFFF;
            lx = plds[bp * 3 + 0]; ly = plds[bp * 3 + 1]; lz = plds[bp * 3 + 2];
            if (t == 0) idxL[m] = bp;
        }
        __syncthreads();
        for (int m = t; m < MS; m += 256) {
            int ix = idxL[m];
            size_t o = (size_t)b * MS + m;
            fps_idx[o] = ix;
            out_pos[o * 3 + 0] = plds[ix * 3 + 0];
            out_pos[o * 3 + 1] = plds[ix * 3 + 1];
            out_pos[o * 3 + 2] = plds[ix * 3 + 2];
            out_batch[o] = (float)b;
        }
    } else if (b < 272) {
        // ---------------- GEMM + BN stats (rows (b-16)*256 .. +255)
        float* wt = smem;            // [128][68] W^T
        float* fl = smem + 8704;     // [64][68] feature tile
#pragma unroll
        for (int it = 0; it < 8; it++) {
            int lid = t + 256 * it;
            int k = lid >> 5, c4 = lid & 31;
            float4 v = *(const float4*)&W[k * FOUT + c4 * 4];
            wt[(c4 * 4 + 0) * 68 + k] = v.x;
            wt[(c4 * 4 + 1) * 68 + k] = v.y;
            wt[(c4 * 4 + 2) * 68 + k] = v.z;
            wt[(c4 * 4 + 3) * 68 + k] = v.w;
        }
        const int rowbase0 = (b - 16) * 256;
        const int rg = t >> 4, cg = t & 15;
        float sums[8] = {0, 0, 0, 0, 0, 0, 0, 0};
        float sqs[8]  = {0, 0, 0, 0, 0, 0, 0, 0};
        for (int sub = 0; sub < 4; sub++) {
            const int rowbase = rowbase0 + sub * 64;
            __syncthreads();
#pragma unroll
            for (int it = 0; it < 4; it++) {
                int lid = t + 256 * it;
                int r = lid >> 4, f4 = lid & 15;
                float4 v = *(const float4*)&feat[(size_t)(rowbase + r) * FIN + f4 * 4];
                *(float4*)&fl[r * 68 + f4 * 4] = v;
            }
            __syncthreads();
            float acc[4][8];
#pragma unroll
            for (int i = 0; i < 4; i++)
#pragma unroll
                for (int j = 0; j < 8; j++) acc[i][j] = 0.f;
#pragma unroll 2
            for (int k4 = 0; k4 < 16; k4++) {
                float4 f4v[4], w4v[8];
#pragma unroll
                for (int i = 0; i < 4; i++) f4v[i] = *(float4*)&fl[(rg * 4 + i) * 68 + k4 * 4];
#pragma unroll
                for (int j = 0; j < 8; j++) w4v[j] = *(float4*)&wt[(cg + 16 * j) * 68 + k4 * 4];
#pragma unroll
                for (int i = 0; i < 4; i++)
#pragma unroll
                    for (int j = 0; j < 8; j++) {
                        acc[i][j] = fmaf(f4v[i].x, w4v[j].x, acc[i][j]);
                        acc[i][j] = fmaf(f4v[i].y, w4v[j].y, acc[i][j]);
                        acc[i][j] = fmaf(f4v[i].z, w4v[j].z, acc[i][j]);
                        acc[i][j] = fmaf(f4v[i].w, w4v[j].w, acc[i][j]);
                    }
            }
#pragma unroll
            for (int j = 0; j < 8; j++) {
                int c = cg + 16 * j;
                float bc = bias[c];
#pragma unroll
                for (int i = 0; i < 4; i++) {
                    float h = acc[i][j] + bc;
                    sums[j] += h; sqs[j] += h * h;
                    hout[(size_t)(rowbase + rg * 4 + i) * FOUT + c] = __float2bfloat16(h);
                }
            }
        }
        __syncthreads();
        float* suml = fl;
        float* sql  = wt;
#pragma unroll
        for (int j = 0; j < 8; j++) {
            suml[rg * FOUT + cg + 16 * j] = sums[j];
            sql[rg * FOUT + cg + 16 * j]  = sqs[j];
        }
        __syncthreads();
        if (t < FOUT) {
            float S = 0.f, Q = 0.f;
#pragma unroll
            for (int r = 0; r < 16; r++) { S += suml[r * FOUT + t]; Q += sql[r * FOUT + t]; }
            atomicAdd(&gsum[t], S);
            atomicAdd(&gsq[t], Q);
        }
    } else {
        // ---------------- xnorm
        int r = (b - 272) * 256 + t;
        const float4* fr = (const float4*)&feat[(size_t)r * FIN];
        float s = 0.f;
#pragma unroll
        for (int i = 0; i < 16; i++) {
            float4 v = fr[i];
            s += v.x * v.x + v.y * v.y + v.z * v.z + v.w * v.w;
        }
        xnorm[r] = s;
    }
}

// ---------------------------------------------------------------- BN finalize
__global__ void finalize_kernel(const float* __restrict__ gsum, const float* __restrict__ gsq,
        const float* __restrict__ gamma, const float* __restrict__ beta,
        float* __restrict__ acoef, float* __restrict__ ccoef) {
    int c = threadIdx.x;
    float mean = gsum[c] * (1.0f / NN);
    float var  = gsq[c] * (1.0f / NN) - mean * mean;
    float s = rsqrtf(var + 1e-5f) * gamma[c];
    acoef[c] = s;
    ccoef[c] = beta[c] - mean * s;
}

// ---------------------------------------------------------------- KNN (quarter point range per block)
__global__ __launch_bounds__(256) void knn_kernel(
        const float* __restrict__ feat, const int* __restrict__ fps_idx,
        const float* __restrict__ xnorm, float* __restrict__ cand_d, int* __restrict__ cand_i) {
    __shared__ float smem[12864];
    float* qlds = smem;            // [64][68]
    float* xlds = smem + 4352;     // [64][68]
    float* slds = smem + 8704;     // [64 p][65] scores p-major
    const int t = threadIdx.x, b = blockIdx.x;
    const int cloud = b & 15;              // cloud <-> XCD locality (b%8 fixed per cloud)
    const int qgroup = (b >> 4) & 15;
    const int quarter = b >> 8;
    const int qbase = qgroup * 64;
    const float* fb = feat + (size_t)cloud * NP * FIN;
    const float* xb = fb + (size_t)quarter * 1024 * FIN;
    const float* xn = xnorm + cloud * NP + quarter * 1024;

    {   // stage queries
        int q = t >> 2, f4 = t & 3;
        int qrow = fps_idx[cloud * MS + qbase + q];
#pragma unroll
        for (int j = 0; j < 4; j++) {
            float4 v = *(const float4*)&fb[(size_t)qrow * FIN + (f4 + 4 * j) * 4];
            *(float4*)&qlds[q * 68 + (f4 + 4 * j) * 4] = v;
        }
    }
    const int pr = t >> 2, pf4 = t & 3;
    float4 pf[4];
#pragma unroll
    for (int j = 0; j < 4; j++)
        pf[j] = *(const float4*)&xb[(size_t)pr * FIN + (pf4 + 4 * j) * 4];

    float d16[16]; int i16[16];
#pragma unroll
    for (int s = 0; s < 16; s++) { d16[s] = INFINITY; i16[s] = 0; }
    const int tq = t >> 4, tp = t & 15;
    const int qq = t >> 2, sub = t & 3;

    for (int ch = 0; ch < 16; ch++) {
        const int pbase = ch * 64;
#pragma unroll
        for (int j = 0; j < 4; j++)
            *(float4*)&xlds[pr * 68 + (pf4 + 4 * j) * 4] = pf[j];
        __syncthreads();
        if (ch < 15) {   // prefetch next chunk across the compute phase
#pragma unroll
            for (int j = 0; j < 4; j++)
                pf[j] = *(const float4*)&xb[(size_t)(pbase + 64 + pr) * FIN + (pf4 + 4 * j) * 4];
        }
        float xnv[4];
#pragma unroll
        for (int j = 0; j < 4; j++) xnv[j] = xn[pbase + tp + 16 * j];
        float acc[4][4];
#pragma unroll
        for (int i = 0; i < 4; i++)
#pragma unroll
            for (int j = 0; j < 4; j++) acc[i][j] = 0.f;
#pragma unroll 4
        for (int k4 = 0; k4 < 16; k4++) {
            float4 q4[4], x4[4];
#pragma unroll
            for (int i = 0; i < 4; i++) q4[i] = *(float4*)&qlds[(tq + 16 * i) * 68 + k4 * 4];
#pragma unroll
            for (int j = 0; j < 4; j++) x4[j] = *(float4*)&xlds[(tp + 16 * j) * 68 + k4 * 4];
#pragma unroll
            for (int i = 0; i < 4; i++)
#pragma unroll
                for (int j = 0; j < 4; j++) {
                    acc[i][j] = fmaf(q4[i].x, x4[j].x, acc[i][j]);
                    acc[i][j] = fmaf(q4[i].y, x4[j].y, acc[i][j]);
                    acc[i][j] = fmaf(q4[i].z, x4[j].z, acc[i][j]);
                    acc[i][j] = fmaf(q4[i].w, x4[j].w, acc[i][j]);
                }
        }
#pragma unroll
        for (int j = 0; j < 4; j++)
#pragma unroll
            for (int i = 0; i < 4; i++)
                slds[(tp + 16 * j) * 65 + tq + 16 * i] = xnv[j] - 2.0f * acc[i][j];
        __syncthreads();
        // scan: thread owns query qq, contiguous p-quarter [sub*16, sub*16+16)
#pragma unroll 4
        for (int k = 0; k < 16; k++) {
            int pl = sub * 16 + k;
            float s = slds[pl * 65 + qq];
            if (s < d16[15]) {
                int gp = quarter * 1024 + pbase + pl;
                bool p_prev, p_cur;
                p_cur = (s < d16[15]);
#pragma unroll
                for (int x = 15; x >= 1; x--) {
                    p_prev = (s < d16[x - 1]);
                    d16[x] = p_cur ? (p_prev ? d16[x - 1] : s) : d16[x];
                    i16[x] = p_cur ? (p_prev ? i16[x - 1] : gp) : i16[x];
                    p_cur = p_prev;
                }
                if (p_cur) { d16[0] = s; i16[0] = gp; }
            }
        }
    }
    // -------- block-level merge: 4 sorted lists per q -> sorted 16, write per-quarter candidates
    __syncthreads();
    float* mD = qlds;
    int*   mI = (int*)xlds;
#pragma unroll
    for (int r = 0; r < 16; r++) {
        mD[(qq * 4 + sub) * 16 + r] = d16[r];
        mI[(qq * 4 + sub) * 16 + r] = i16[r];
    }
    __syncthreads();
    float* sD = slds;
    int*   sI = ((int*)slds) + 2048;
    if (t < 128) {
        int q = t >> 1, u = t & 1;
        float oD[16]; int oI[16];
        merge16(&mD[(q * 4 + 2 * u) * 16], &mI[(q * 4 + 2 * u) * 16],
                &mD[(q * 4 + 2 * u + 1) * 16], &mI[(q * 4 + 2 * u + 1) * 16], oD, oI);
#pragma unroll
        for (int r = 0; r < 16; r++) { sD[(q * 2 + u) * 16 + r] = oD[r]; sI[(q * 2 + u) * 16 + r] = oI[r]; }
    }
    __syncthreads();
    if (t < 64) {
        float oD[16]; int oI[16];
        merge16(&sD[t * 32], &sI[t * 32], &sD[t * 32 + 16], &sI[t * 32 + 16], oD, oI);
        size_t off = ((size_t)(cloud * MS + qbase + t) * 4 + quarter) * 16;
#pragma unroll
        for (int r = 0; r < 16; r++) { cand_d[off + r] = oD[r]; cand_i[off + r] = oI[r]; }
    }
}

// ---------------------------------------------------------------- merge quarters + gather + BN/ReLU + maxpool
__global__ __launch_bounds__(256) void gather_kernel(
        const float* __restrict__ cand_d, const int* __restrict__ cand_i,
        const __hip_bfloat16* __restrict__ h, const float* __restrict__ acoef,
        const float* __restrict__ ccoef, float* __restrict__ out_feat) {
    __shared__ float tD[4][16];
    __shared__ int   tI[4][16];
    __shared__ int   fI[2][16];
    __shared__ float cf[256];
    const int t = threadIdx.x, b = blockIdx.x;
    const int cloud = b & 15;            // cloud <-> XCD locality for h
    const int qpair = b >> 4;            // 0..511
    if (t < 128) cf[t] = acoef[t]; else cf[t] = ccoef[t - 128];
    if (t < 4) {
        int ql = t >> 1, u = t & 1;
        int q = cloud * MS + qpair * 2 + ql;
        size_t base = (size_t)q * 64 + u * 32;
        float oD[16]; int oI[16];
        merge16(&cand_d[base], &cand_i[base], &cand_d[base + 16], &cand_i[base + 16], oD, oI);
#pragma unroll
        for (int r = 0; r < 16; r++) { tD[t][r] = oD[r]; tI[t][r] = oI[r]; }
    }
    __syncthreads();
    if (t < 2) {
        float oD[16]; int oI[16];
        merge16(tD[t * 2], tI[t * 2], tD[t * 2 + 1], tI[t * 2 + 1], oD, oI);
#pragma unroll
        for (int r = 0; r < 16; r++) fI[t][r] = oI[r];
    }
    __syncthreads();
    const int ql = t >> 7, c = t & 127;
    const int q = cloud * MS + qpair * 2 + ql;
    const __hip_bfloat16* hb = h + (size_t)cloud * NP * FOUT;
    const float ac = cf[c], cc = cf[128 + c];
    float mx = -INFINITY;
#pragma unroll
    for (int k = 0; k < 16; k++) {
        int row = fI[ql][k];
        float hv = __bfloat162float(hb[(size_t)row * FOUT + c]);
        mx = fmaxf(mx, fmaxf(fmaf(ac, hv, cc), 0.f));
    }
    out_feat[(size_t)q * FOUT + c] = mx;
}

// ---------------------------------------------------------------- launch
extern "C" void kernel_launch(void* const* d_in, const int* in_sizes, int n_in,
                              void* d_out, int out_size, void* d_ws, size_t ws_size,
                              hipStream_t stream) {
    (void)in_sizes; (void)n_in; (void)out_size; (void)ws_size;
    const float* position = (const float*)d_in[0];
    const float* features = (const float*)d_in[1];
    const float* W        = (const float*)d_in[3];
    const float* bias     = (const float*)d_in[4];
    const float* gamma    = (const float*)d_in[5];
    const float* beta     = (const float*)d_in[6];
    float* out = (float*)d_out;

    char* ws = (char*)d_ws;
    int*   fps_idx = (int*)ws;                              // 65536 B
    float* gsum    = (float*)(ws + 65536);                  // 512 B
    float* gsq     = (float*)(ws + 66048);                  // 512 B
    float* xnorm   = (float*)(ws + 66560);                  // 262144 B
    float* acoef   = (float*)(ws + 328704);                 // 512 B
    float* ccoef   = (float*)(ws + 329216);                 // 512 B
    float* cand_d  = (float*)(ws + 331776);                 // 4 MB
    int*   cand_i  = (int*)(ws + 4526080);                  // 4 MB
    __hip_bfloat16* hbuf = (__hip_bfloat16*)(ws + 8720384); // 16.78 MB

    float* out_feat  = out;                 // [16384][128]
    float* out_pos   = out + 2097152;       // [16384][3]
    float* out_batch = out + 2146304;       // [16384]

    hipMemsetAsync(gsum, 0, 1024, stream);  // zero gsum+gsq
    front_kernel<<<528, 256, 0, stream>>>(position, features, W, bias,
                                          fps_idx, out_pos, out_batch, xnorm, hbuf, gsum, gsq);
    finalize_kernel<<<1, FOUT, 0, stream>>>(gsum, gsq, gamma, beta, acoef, ccoef);
    knn_kernel<<<1024, 256, 0, stream>>>(features, fps_idx, xnorm, cand_d, cand_i);
    gather_kernel<<<8192, 256, 0, stream>>>(cand_d, cand_i, hbuf, acoef, ccoef, out_feat);
}

// Round 4
// 1164.227 us; speedup vs baseline: 1.1599x; 1.1599x over previous
//
#include <hip/hip_runtime.h>
#include <hip/hip_bf16.h>

#define NB 16
#define NP 4096
#define MS 1024
#define NN 65536
#define FIN 64
#define FOUT 128
#define XPARTS 8
#define XROWS (NP / XPARTS)   // 512

// DPP cumulative-max step (VALU pipe, no LDS)
template <int CTRL>
__device__ __forceinline__ unsigned long long dpp_max_step(unsigned long long k) {
    unsigned lo = (unsigned)k, hi = (unsigned)(k >> 32);
    unsigned plo = (unsigned)__builtin_amdgcn_update_dpp(0, (int)lo, CTRL, 0xf, 0xf, true);
    unsigned phi = (unsigned)__builtin_amdgcn_update_dpp(0, (int)hi, CTRL, 0xf, 0xf, true);
    unsigned long long pk = ((unsigned long long)phi << 32) | plo;   // invalid lanes -> 0 (identity)
    return pk > k ? pk : k;
}

// merge two sorted (d asc, idx asc) 16-lists -> top-16, lex order matches top_k ties
__device__ __forceinline__ void merge16(const float* __restrict__ dA, const int* __restrict__ iA,
                                        const float* __restrict__ dB, const int* __restrict__ iB,
                                        float* __restrict__ oD, int* __restrict__ oI) {
    int x = 0, y = 0;
#pragma unroll
    for (int r = 0; r < 16; r++) {
        int xc = x < 16 ? x : 15, yc = y < 16 ? y : 15;
        float va = dA[xc]; int ja = iA[xc];
        float vb = dB[yc]; int jb = iB[yc];
        bool ta = (y >= 16) || ((x < 16) && (va < vb || (va == vb && ja < jb)));
        oD[r] = ta ? va : vb;
        oI[r] = ta ? ja : jb;
        if (ta) x++; else y++;
    }
}

// ---------------------------------------------------------------- front: FPS + GEMM + xnorm fused
__global__ __launch_bounds__(512, 1) void front_kernel(
        const float* __restrict__ pos, const float* __restrict__ feat,
        const float* __restrict__ W, const float* __restrict__ bias,
        int* __restrict__ fps_idx, float* __restrict__ out_pos, float* __restrict__ out_batch,
        float* __restrict__ xnorm, __hip_bfloat16* __restrict__ hout,
        float* __restrict__ gsum, float* __restrict__ gsq) {
    __shared__ float smem[13344];
    const int t = threadIdx.x;
    const int b = blockIdx.x;
    if (b < 16) {
        // ---------------- FPS: 512 threads x 8 pts/thread (32 regs of state -> no spills)
        float* plds = smem;                                   // 12288 floats
        int* idxL = (int*)(smem + 12288);                     // 1024 ints
        unsigned long long* rk = (unsigned long long*)(smem + 13312);  // 16 u64
        const float* pb = pos + (size_t)b * NP * 3;
#pragma unroll
        for (int i = 0; i < 24; i++) { int id = t + 512 * i; plds[id] = pb[id]; }
        __syncthreads();
        float px[8], py[8], pz[8], dist[8];
#pragma unroll
        for (int i = 0; i < 8; i++) {
            int p = t + 512 * i;
            px[i] = plds[p * 3 + 0]; py[i] = plds[p * 3 + 1]; pz[i] = plds[p * 3 + 2];
            dist[i] = INFINITY;
        }
        float lx = plds[0], ly = plds[1], lz = plds[2];
        if (t == 0) idxL[0] = 0;
        const int ln = t & 63, wv = t >> 6;   // 8 waves
        for (int m = 1; m < MS; m++) {
            // independent distance updates (exact same arithmetic as validated rounds)
#pragma unroll
            for (int i = 0; i < 8; i++) {
                float dx = px[i] - lx, dy = py[i] - ly, dz = pz[i] - lz;
                float d = dx * dx + dy * dy + dz * dz;
                dist[i] = fminf(dist[i], d);
            }
            // in-thread argmax: 3-level tree over 8
            float d1[4]; int i1[4];
#pragma unroll
            for (int i = 0; i < 4; i++) {
                bool g = dist[i + 4] > dist[i];
                d1[i] = g ? dist[i + 4] : dist[i]; i1[i] = g ? (i + 4) : i;
            }
            float d2[2]; int i2[2];
#pragma unroll
            for (int i = 0; i < 2; i++) {
                bool g = d1[i + 2] > d1[i];
                d2[i] = g ? d1[i + 2] : d1[i]; i2[i] = g ? i1[i + 2] : i1[i];
            }
            bool g3 = d2[1] > d2[0];
            float bd = g3 ? d2[1] : d2[0];
            int bi = g3 ? i2[1] : i2[0];
            int bp = t + (bi << 9);
            unsigned long long key =
                ((unsigned long long)__float_as_uint(bd) << 32) | (unsigned)(~bp);
            key = dpp_max_step<0x111>(key);   // row_shr:1
            key = dpp_max_step<0x112>(key);   // row_shr:2
            key = dpp_max_step<0x114>(key);   // row_shr:4
            key = dpp_max_step<0x118>(key);   // row_shr:8
            key = dpp_max_step<0x142>(key);   // row_bcast15
            key = dpp_max_step<0x143>(key);   // row_bcast31
            const int par = (m & 1) * 8;
            if (ln == 63) rk[par + wv] = key;
            __syncthreads();
            unsigned long long k0 = rk[par + 0], k1 = rk[par + 1];
            unsigned long long k2 = rk[par + 2], k3 = rk[par + 3];
            unsigned long long k4 = rk[par + 4], k5 = rk[par + 5];
            unsigned long long k6 = rk[par + 6], k7 = rk[par + 7];
            unsigned long long ka = k0 > k1 ? k0 : k1;
            unsigned long long kb = k2 > k3 ? k2 : k3;
            unsigned long long kc = k4 > k5 ? k4 : k5;
            unsigned long long kd = k6 > k7 ? k6 : k7;
            ka = ka > kb ? ka : kb;
            kc = kc > kd ? kc : kd;
            unsigned long long kw = ka > kc ? ka : kc;
            bp = (int)(~(unsigned)kw) & 0xFFF;
            lx = plds[bp * 3 + 0]; ly = plds[bp * 3 + 1]; lz = plds[bp * 3 + 2];
            if (t == 0) idxL[m] = bp;
        }
        __syncthreads();
        for (int m = t; m < MS; m += 512) {
            int ix = idxL[m];
            size_t o = (size_t)b * MS + m;
            fps_idx[o] = ix;
            out_pos[o * 3 + 0] = plds[ix * 3 + 0];
            out_pos[o * 3 + 1] = plds[ix * 3 + 1];
            out_pos[o * 3 + 2] = plds[ix * 3 + 2];
            out_batch[o] = (float)b;
        }
    } else if (b < 272) {
        // ---------------- GEMM + BN stats (rows (b-16)*256 .. +255), 512 threads
        float* wt = smem;            // [128][68] W^T
        float* fl = smem + 8704;     // [64][68] feature tile
#pragma unroll
        for (int it = 0; it < 4; it++) {               // stage W -> wt (transposed)
            int lid = t + 512 * it;                    // 2048 float4s
            int k = lid >> 5, c4 = lid & 31;
            float4 v = *(const float4*)&W[k * FOUT + c4 * 4];
            wt[(c4 * 4 + 0) * 68 + k] = v.x;
            wt[(c4 * 4 + 1) * 68 + k] = v.y;
            wt[(c4 * 4 + 2) * 68 + k] = v.z;
            wt[(c4 * 4 + 3) * 68 + k] = v.w;
        }
        const int rowbase0 = (b - 16) * 256;
        const int rg = t >> 5, cg = t & 31;
        float sums[4] = {0, 0, 0, 0};
        float sqs[4]  = {0, 0, 0, 0};
        for (int sub = 0; sub < 4; sub++) {
            const int rowbase = rowbase0 + sub * 64;
            __syncthreads();
#pragma unroll
            for (int it = 0; it < 2; it++) {           // stage 64 feature rows
                int lid = t + 512 * it;
                int r = lid >> 4, f4 = lid & 15;
                float4 v = *(const float4*)&feat[(size_t)(rowbase + r) * FIN + f4 * 4];
                *(float4*)&fl[r * 68 + f4 * 4] = v;
            }
            __syncthreads();
            float acc[4][4];
#pragma unroll
            for (int i = 0; i < 4; i++)
#pragma unroll
                for (int j = 0; j < 4; j++) acc[i][j] = 0.f;
#pragma unroll 2
            for (int k4 = 0; k4 < 16; k4++) {
                float4 f4v[4], w4v[4];
#pragma unroll
                for (int i = 0; i < 4; i++) f4v[i] = *(float4*)&fl[(rg * 4 + i) * 68 + k4 * 4];
#pragma unroll
                for (int j = 0; j < 4; j++) w4v[j] = *(float4*)&wt[(cg + 32 * j) * 68 + k4 * 4];
#pragma unroll
                for (int i = 0; i < 4; i++)
#pragma unroll
                    for (int j = 0; j < 4; j++) {
                        acc[i][j] = fmaf(f4v[i].x, w4v[j].x, acc[i][j]);
                        acc[i][j] = fmaf(f4v[i].y, w4v[j].y, acc[i][j]);
                        acc[i][j] = fmaf(f4v[i].z, w4v[j].z, acc[i][j]);
                        acc[i][j] = fmaf(f4v[i].w, w4v[j].w, acc[i][j]);
                    }
            }
#pragma unroll
            for (int j = 0; j < 4; j++) {
                int c = cg + 32 * j;
                float bc = bias[c];
#pragma unroll
                for (int i = 0; i < 4; i++) {
                    float h = acc[i][j] + bc;
                    sums[j] += h; sqs[j] += h * h;
                    hout[(size_t)(rowbase + rg * 4 + i) * FOUT + c] = __float2bfloat16(h);
                }
            }
        }
        __syncthreads();
        float* suml = fl;   // 16*128 = 2048 floats
        float* sql  = wt;
#pragma unroll
        for (int j = 0; j < 4; j++) {
            suml[rg * FOUT + cg + 32 * j] = sums[j];
            sql[rg * FOUT + cg + 32 * j]  = sqs[j];
        }
        __syncthreads();
        if (t < FOUT) {
            float S = 0.f, Q = 0.f;
#pragma unroll
            for (int r = 0; r < 16; r++) { S += suml[r * FOUT + t]; Q += sql[r * FOUT + t]; }
            atomicAdd(&gsum[t], S);
            atomicAdd(&gsq[t], Q);
        }
    } else {
        // ---------------- xnorm (512 threads, 128 blocks)
        int r = (b - 272) * 512 + t;
        const float4* fr = (const float4*)&feat[(size_t)r * FIN];
        float s = 0.f;
#pragma unroll
        for (int i = 0; i < 16; i++) {
            float4 v = fr[i];
            s += v.x * v.x + v.y * v.y + v.z * v.z + v.w * v.w;
        }
        xnorm[r] = s;
    }
}

// ---------------------------------------------------------------- BN finalize
__global__ void finalize_kernel(const float* __restrict__ gsum, const float* __restrict__ gsq,
        const float* __restrict__ gamma, const float* __restrict__ beta,
        float* __restrict__ acoef, float* __restrict__ ccoef) {
    int c = threadIdx.x;
    float mean = gsum[c] * (1.0f / NN);
    float var  = gsq[c] * (1.0f / NN) - mean * mean;
    float s = rsqrtf(var + 1e-5f) * gamma[c];
    acoef[c] = s;
    ccoef[c] = beta[c] - mean * s;
}

// ---------------------------------------------------------------- KNN: query-in-registers, uniform x
// thread = one query (64 regs); x rows are wave-uniform loads (scalarized -> SMEM, no LDS pipe).
__global__ __launch_bounds__(256, 2) void knn_kernel(
        const float* __restrict__ feat, const int* __restrict__ fps_idx,
        const float* __restrict__ xnorm, float* __restrict__ cand_d, int* __restrict__ cand_i) {
    const int t = threadIdx.x, b = blockIdx.x;
    const int cloud = b & 15;              // cloud <-> XCD locality
    const int qb = (b >> 4) & 3;
    const int xp = b >> 6;                 // 0..7
    const float* fb = feat + (size_t)cloud * NP * FIN;
    const int qrow = fps_idx[cloud * MS + qb * 256 + t];
    float q[64];
    {
        const float4* qr = (const float4*)(fb + (size_t)qrow * FIN);
#pragma unroll
        for (int i = 0; i < 16; i++) {
            float4 v = qr[i];
            q[4 * i + 0] = v.x; q[4 * i + 1] = v.y; q[4 * i + 2] = v.z; q[4 * i + 3] = v.w;
        }
    }
    float d16[16]; int i16[16];
#pragma unroll
    for (int s = 0; s < 16; s++) { d16[s] = INFINITY; i16[s] = 0; }

    const float* xb = fb + (size_t)xp * XROWS * FIN;
    const float* xn = xnorm + cloud * NP + xp * XROWS;

    float h0[32], h1[32];                  // uniform half-row double buffer
#pragma unroll
    for (int j = 0; j < 32; j++) h0[j] = xb[j];

#pragma unroll 1
    for (int p = 0; p < XROWS; p++) {
        const float* xr = xb + (size_t)p * FIN;
        // issue second-half loads, then compute first half (overlap)
#pragma unroll
        for (int j = 0; j < 32; j++) h1[j] = xr[32 + j];
        float a0 = 0.f, a1 = 0.f, a2 = 0.f, a3 = 0.f;
#pragma unroll
        for (int j = 0; j < 8; j++) {
            a0 = fmaf(q[4 * j + 0], h0[4 * j + 0], a0);
            a1 = fmaf(q[4 * j + 1], h0[4 * j + 1], a1);
            a2 = fmaf(q[4 * j + 2], h0[4 * j + 2], a2);
            a3 = fmaf(q[4 * j + 3], h0[4 * j + 3], a3);
        }
        float xnp = xn[p];
        // issue next-row first-half loads, then compute second half (overlap)
        if (p < XROWS - 1) {
#pragma unroll
            for (int j = 0; j < 32; j++) h0[j] = xr[FIN + j];
        }
#pragma unroll
        for (int j = 0; j < 8; j++) {
            a0 = fmaf(q[32 + 4 * j + 0], h1[4 * j + 0], a0);
            a1 = fmaf(q[32 + 4 * j + 1], h1[4 * j + 1], a1);
            a2 = fmaf(q[32 + 4 * j + 2], h1[4 * j + 2], a2);
            a3 = fmaf(q[32 + 4 * j + 3], h1[4 * j + 3], a3);
        }
        float dot = (a0 + a1) + (a2 + a3);
        float s = fmaf(-2.0f, dot, xnp);
        if (s < d16[15]) {                 // sorted insertion, ties keep earlier (lower) index
            int gp = xp * XROWS + p;
            bool p_prev, p_cur = true;
#pragma unroll
            for (int x = 15; x >= 1; x--) {
                p_prev = (s < d16[x - 1]);
                d16[x] = p_cur ? (p_prev ? d16[x - 1] : s) : d16[x];
                i16[x] = p_cur ? (p_prev ? i16[x - 1] : gp) : i16[x];
                p_cur = p_prev;
            }
            if (p_cur) { d16[0] = s; i16[0] = gp; }
        }
    }
    size_t off = ((size_t)(cloud * MS + qb * 256 + t)) * (XPARTS * 16) + xp * 16;
#pragma unroll
    for (int r = 0; r < 16; r++) { cand_d[off + r] = d16[r]; cand_i[off + r] = i16[r]; }
}

// ---------------------------------------------------------------- merge 8 lists + gather + BN/ReLU + maxpool
__global__ __launch_bounds__(256) void gather_kernel(
        const float* __restrict__ cand_d, const int* __restrict__ cand_i,
        const __hip_bfloat16* __restrict__ h, const float* __restrict__ acoef,
        const float* __restrict__ ccoef, float* __restrict__ out_feat) {
    __shared__ float sd[2][8][16];
    __shared__ int   si[2][8][16];
    __shared__ float l1d[2][4][16];
    __shared__ int   l1i[2][4][16];
    __shared__ float l2d[2][2][16];
    __shared__ int   l2i[2][2][16];
    __shared__ int   fI[2][16];
    __shared__ float cf[256];
    const int t = threadIdx.x, b = blockIdx.x;
    const int cloud = b & 15;
    const int qpair = b >> 4;              // 0..511
    const int q0 = cloud * MS + qpair * 2;
    if (t < 128) cf[t] = acoef[t]; else cf[t] = ccoef[t - 128];
    {   // coalesced stage of both queries' 8x16 candidates
        int qloc = t >> 7, rest = t & 127;
        int part = rest >> 4, r = rest & 15;
        size_t off = (size_t)(q0 + qloc) * 128 + part * 16 + r;
        sd[qloc][part][r] = cand_d[off];
        si[qloc][part][r] = cand_i[off];
    }
    __syncthreads();
    if (t < 8) {
        int qloc = t >> 2, pr = t & 3;
        float oD[16]; int oI[16];
        merge16(sd[qloc][2 * pr], si[qloc][2 * pr], sd[qloc][2 * pr + 1], si[qloc][2 * pr + 1], oD, oI);
#pragma unroll
        for (int r = 0; r < 16; r++) { l1d[qloc][pr][r] = oD[r]; l1i[qloc][pr][r] = oI[r]; }
    }
    __syncthreads();
    if (t < 4) {
        int qloc = t >> 1, v = t & 1;
        float oD[16]; int oI[16];
        merge16(l1d[qloc][2 * v], l1i[qloc][2 * v], l1d[qloc][2 * v + 1], l1i[qloc][2 * v + 1], oD, oI);
#pragma unroll
        for (int r = 0; r < 16; r++) { l2d[qloc][v][r] = oD[r]; l2i[qloc][v][r] = oI[r]; }
    }
    __syncthreads();
    if (t < 2) {
        float oD[16]; int oI[16];
        merge16(l2d[t][0], l2i[t][0], l2d[t][1], l2i[t][1], oD, oI);
#pragma unroll
        for (int r = 0; r < 16; r++) fI[t][r] = oI[r];
    }
    __syncthreads();
    const int ql = t >> 7, c = t & 127;
    const int q = q0 + ql;
    const __hip_bfloat16* hb = h + (size_t)cloud * NP * FOUT;
    const float ac = cf[c], cc = cf[128 + c];
    float mx = -INFINITY;
#pragma unroll
    for (int k = 0; k < 16; k++) {
        int row = fI[ql][k];
        float hv = __bfloat162float(hb[(size_t)row * FOUT + c]);
        mx = fmaxf(mx, fmaxf(fmaf(ac, hv, cc), 0.f));
    }
    out_feat[(size_t)q * FOUT + c] = mx;
}

// ---------------------------------------------------------------- launch
extern "C" void kernel_launch(void* const* d_in, const int* in_sizes, int n_in,
                              void* d_out, int out_size, void* d_ws, size_t ws_size,
                              hipStream_t stream) {
    (void)in_sizes; (void)n_in; (void)out_size; (void)ws_size;
    const float* position = (const float*)d_in[0];
    const float* features = (const float*)d_in[1];
    const float* W        = (const float*)d_in[3];
    const float* bias     = (const float*)d_in[4];
    const float* gamma    = (const float*)d_in[5];
    const float* beta     = (const float*)d_in[6];
    float* out = (float*)d_out;

    char* ws = (char*)d_ws;
    int*   fps_idx = (int*)ws;                               // 65536 B
    float* gsum    = (float*)(ws + 65536);                   // 512 B
    float* gsq     = (float*)(ws + 66048);                   // 512 B
    float* xnorm   = (float*)(ws + 66560);                   // 262144 B
    float* acoef   = (float*)(ws + 328704);                  // 512 B
    float* ccoef   = (float*)(ws + 329216);                  // 512 B
    float* cand_d  = (float*)(ws + 331776);                  // 8 MB
    int*   cand_i  = (int*)(ws + 8720384);                   // 8 MB
    __hip_bfloat16* hbuf = (__hip_bfloat16*)(ws + 17108992); // 16.78 MB

    float* out_feat  = out;                 // [16384][128]
    float* out_pos   = out + 2097152;       // [16384][3]
    float* out_batch = out + 2146304;       // [16384]

    hipMemsetAsync(gsum, 0, 1024, stream);  // zero gsum+gsq
    front_kernel<<<400, 512, 0, stream>>>(position, features, W, bias,
                                          fps_idx, out_pos, out_batch, xnorm, hbuf, gsum, gsq);
    finalize_kernel<<<1, FOUT, 0, stream>>>(gsum, gsq, gamma, beta, acoef, ccoef);
    knn_kernel<<<512, 256, 0, stream>>>(features, fps_idx, xnorm, cand_d, cand_i);
    gather_kernel<<<8192, 256, 0, stream>>>(cand_d, cand_i, hbuf, acoef, ccoef, out_feat);
}